// Round 10
// baseline (446.867 us; speedup 1.0000x reference)
//
#include <hip/hip_runtime.h>

// AttentionCTS: qkv proj -> depthwise 3x3 conv -> temporal mix -> L2-norm
// q,k -> softmax(q k^T * temp) v -> out proj.   All f32 (no fp32 MFMA on CDNA4).

#define BB   4
#define DIM  64
#define HEADS 4
#define TT   10
#define HH   64
#define WW2  64
#define HW   4096          // HH*WW2
#define CPH  16            // DIM/HEADS
#define NQ   160           // CPH*TT
#define C3   192           // 3*DIM
#define NSPLIT 8           // d-splits for scores

// ---------------- Kernel 0: weight transpose (tiny) ------------------------------
__global__ __launch_bounds__(256) void k_transpose(const float* __restrict__ w,
                                                   float* __restrict__ wT,
                                                   int O, int C) {
    int idx = blockIdx.x * 256 + threadIdx.x;
    if (idx < O * C) {
        int o = idx / C, c = idx - o * C;
        wT[c * O + o] = w[idx];
    }
}

// ---------------- Kernel 1/6: pointwise projection (register-blocked GEMM) -------
template<int CHUNK>
__global__ __launch_bounds__(256) void k_proj(const float* __restrict__ x,
                                              const float* __restrict__ wT,  // [DIM][cout_total]
                                              float* __restrict__ out,
                                              int cout_total) {
    int P   = blockIdx.x * 1024 + threadIdx.x * 4;   // position over (b,t,hw)
    int b   = P / (TT * HW);
    int rem = P - b * (TT * HW);
    int t   = rem >> 12;
    int hw  = rem & 4095;
    int o0  = blockIdx.y * CHUNK;
    const float* xp = x + ((size_t)(b * DIM) * TT + t) * HW + hw;
    float4 acc[CHUNK];
#pragma unroll
    for (int o = 0; o < CHUNK; ++o) acc[o] = make_float4(0.f, 0.f, 0.f, 0.f);
    for (int c = 0; c < DIM; ++c) {
        float4 xv = *(const float4*)(xp + (size_t)c * TT * HW);
        const float* wr = wT + c * cout_total + o0;      // uniform -> s_load x4
#pragma unroll
        for (int o = 0; o < CHUNK; ++o) {
            float wv = wr[o];
            acc[o].x += wv * xv.x;
            acc[o].y += wv * xv.y;
            acc[o].z += wv * xv.z;
            acc[o].w += wv * xv.w;
        }
    }
    float* op = out + ((size_t)b * cout_total * TT + t) * HW + hw;
#pragma unroll
    for (int o = 0; o < CHUNK; ++o)
        *(float4*)(op + (size_t)(o0 + o) * TT * HW) = acc[o];
}

// ---------------- Kernel 2: depthwise 3x3 conv + fused temporal mix + q/k sumsq --
__global__ __launch_bounds__(256) void k_conv_temporal(const float* __restrict__ A,
                                                       const float* __restrict__ wdw,
                                                       const float* __restrict__ wt,
                                                       const float* __restrict__ bt,
                                                       float* __restrict__ Bq,
                                                       float* __restrict__ nbuf) {
    int tid  = threadIdx.x;
    int lane = tid & 63;
    int wv   = tid >> 6;
    int li   = lane & 15;                  // w-group: w = li*4
    int g    = lane >> 4;                  // row within wave's 4-row strip
    int blk  = blockIdx.x;                 // (b*C3 + c)*4 + quarter
    int qt   = blk & 3;
    int c    = (blk >> 2) % C3;
    int b    = blk / (4 * C3);
    int row  = qt * 16 + wv * 4 + g;

    float wd[9];
#pragma unroll
    for (int k = 0; k < 9; ++k) wd[k] = wdw[c * 9 + k];    // uniform -> sgpr

    const float* Ab = A + (size_t)(b * C3 + c) * TT * HW + row * WW2 + li * 4;
    bool hasU = (row > 0), hasD = (row < HH - 1);
    const float4 z4 = make_float4(0.f, 0.f, 0.f, 0.f);

    float4 ov4[TT];
#pragma unroll
    for (int s = 0; s < TT; ++s) {
        float bs = bt[s];
        ov4[s] = make_float4(bs, bs, bs, bs);
    }

    // prefetch t=0
    float4 u = hasU ? *(const float4*)(Ab - WW2) : z4;
    float4 m = *(const float4*)(Ab);
    float4 d = hasD ? *(const float4*)(Ab + WW2) : z4;

#pragma unroll
    for (int t = 0; t < TT; ++t) {
        float4 un, mn, dn;
        if (t < TT - 1) {                   // issue next batch before computing
            const float* p = Ab + (size_t)(t + 1) * HW;
            un = hasU ? *(const float4*)(p - WW2) : z4;
            mn = *(const float4*)(p);
            dn = hasD ? *(const float4*)(p + WW2) : z4;
        }
        float uL = __shfl_up(u.w, 1);   if (li == 0)  uL = 0.f;
        float mL = __shfl_up(m.w, 1);   if (li == 0)  mL = 0.f;
        float dL = __shfl_up(d.w, 1);   if (li == 0)  dL = 0.f;
        float uR = __shfl_down(u.x, 1); if (li == 15) uR = 0.f;
        float mR = __shfl_down(m.x, 1); if (li == 15) mR = 0.f;
        float dR = __shfl_down(d.x, 1); if (li == 15) dR = 0.f;
        float4 r;
        r.x = uL  * wd[0] + u.x * wd[1] + u.y * wd[2]
            + mL  * wd[3] + m.x * wd[4] + m.y * wd[5]
            + dL  * wd[6] + d.x * wd[7] + d.y * wd[8];
        r.y = u.x * wd[0] + u.y * wd[1] + u.z * wd[2]
            + m.x * wd[3] + m.y * wd[4] + m.z * wd[5]
            + d.x * wd[6] + d.y * wd[7] + d.z * wd[8];
        r.z = u.y * wd[0] + u.z * wd[1] + u.w * wd[2]
            + m.y * wd[3] + m.z * wd[4] + m.w * wd[5]
            + d.y * wd[6] + d.z * wd[7] + d.w * wd[8];
        r.w = u.z * wd[0] + u.w * wd[1] + uR  * wd[2]
            + m.z * wd[3] + m.w * wd[4] + mR  * wd[5]
            + d.z * wd[6] + d.w * wd[7] + dR  * wd[8];
#pragma unroll
        for (int s = 0; s < TT; ++s) {      // fused temporal accumulation
            float wv_ = wt[s * TT + t];     // uniform -> s_load
            ov4[s].x += r.x * wv_;
            ov4[s].y += r.y * wv_;
            ov4[s].z += r.z * wv_;
            ov4[s].w += r.w * wv_;
        }
        u = un; m = mn; d = dn;
    }

    size_t obase = (size_t)(b * C3 + c) * TT * HW + row * WW2 + li * 4;
    float ss[TT];
#pragma unroll
    for (int s = 0; s < TT; ++s) {
        *(float4*)(Bq + obase + (size_t)s * HW) = ov4[s];
        ss[s] = ov4[s].x * ov4[s].x + ov4[s].y * ov4[s].y
              + ov4[s].z * ov4[s].z + ov4[s].w * ov4[s].w;
    }

    if (c < 128) {                          // q or k row: accumulate sumsq
#pragma unroll
        for (int off = 32; off > 0; off >>= 1) {
#pragma unroll
            for (int s = 0; s < TT; ++s) ss[s] += __shfl_xor(ss[s], off);
        }
        if (lane == 0) {
#pragma unroll
            for (int s = 0; s < TT; ++s)
                atomicAdd(&nbuf[(size_t)(b * 128 + c) * TT + s], ss[s]);
        }
    }
}

// ---------------- Kernel 3: partial scores S_part[split] = q k^T over d-chunk ----
// 80x80 block tile (NQ=160=2x80), 16x16 thread grid, 5x5 outputs/thread at
// stride 16: per dd 10 ds_read_b128 feed 100 FMAs (10:1, was 4:1) -> VALU-bound.
// Grid 512 = 2 blocks/CU; XCD swizzle keeps each (bh,split) group on one XCD.
__global__ __launch_bounds__(256) void k_scores(const float* __restrict__ Bq,
                                                float* __restrict__ Spart) {
    __shared__ float ldsQ[80 * 68];
    __shared__ float ldsK[80 * 68];
    int gblk    = blockIdx.x;                 // 0..511
    int logical = (gblk & 7) * 64 + (gblk >> 3);
    int split   = logical >> 6;               // 0..7 (one split per XCD)
    int rem     = logical & 63;
    int bh      = rem >> 2;
    int tl      = rem & 3;
    int nt = tl >> 1, mt = tl & 1;
    int b = bh >> 2, h = bh & 3;
    const float* Qb = Bq + ((size_t)(b * C3 + h * CPH) * TT) * HW + (size_t)nt * 80 * HW;
    const float* Kb = Bq + ((size_t)(b * C3 + 64 + h * CPH) * TT) * HW + (size_t)mt * 80 * HW;
    int tid = threadIdx.x;
    int qr  = tid >> 4;            // 0..15 (also staging row base)
    int kr  = tid & 15;            // 0..15
    int lc  = kr * 4;              // staging col
    float a[5][5] = {};
    int dlo = split * (HW / NSPLIT), dhi = dlo + (HW / NSPLIT);
    for (int d0 = dlo; d0 < dhi; d0 += 64) {
        __syncthreads();
#pragma unroll
        for (int i = 0; i < 5; ++i) {
            int row = qr + 16 * i;
            *(float4*)(ldsQ + row * 68 + lc) =
                *(const float4*)(Qb + (size_t)row * HW + d0 + lc);
            *(float4*)(ldsK + row * 68 + lc) =
                *(const float4*)(Kb + (size_t)row * HW + d0 + lc);
        }
        __syncthreads();
#pragma unroll
        for (int dd = 0; dd < 64; dd += 4) {
            float4 qv[5], kv[5];
#pragma unroll
            for (int i = 0; i < 5; ++i) {
                qv[i] = *(const float4*)(ldsQ + (qr + 16 * i) * 68 + dd);
                kv[i] = *(const float4*)(ldsK + (kr + 16 * i) * 68 + dd);
            }
#pragma unroll
            for (int i = 0; i < 5; ++i)
#pragma unroll
                for (int j = 0; j < 5; ++j)
                    a[i][j] += qv[i].x * kv[j].x + qv[i].y * kv[j].y
                             + qv[i].z * kv[j].z + qv[i].w * kv[j].w;
        }
    }
    int n0 = nt * 80 + qr, m0 = mt * 80 + kr;
#pragma unroll
    for (int i = 0; i < 5; ++i)
#pragma unroll
        for (int j = 0; j < 5; ++j)
            Spart[(size_t)split * (16 * NQ * NQ)
                  + ((size_t)bh * NQ + n0 + 16 * i) * NQ + m0 + 16 * j] = a[i][j];
}

// ---------------- Kernel 4: sum partials, scale, softmax over m, write P^T -------
__global__ __launch_bounds__(256) void k_softmax(const float* __restrict__ Spart,
                                                 const float* __restrict__ nbuf,
                                                 const float* __restrict__ temp,
                                                 float* __restrict__ PT) {
    const int SS = 16 * NQ * NQ;
    int r    = blockIdx.x * 4 + (threadIdx.x >> 6);   // row id 0..2559 (= bh*160+n)
    int lane = threadIdx.x & 63;
    const float* Sr = Spart + (size_t)r * NQ;
    float v0 = 0.f, v1 = 0.f, v2 = 0.f;
#pragma unroll
    for (int sp = 0; sp < NSPLIT; ++sp) {
        v0 += Sr[sp * SS + lane];
        v1 += Sr[sp * SS + lane + 64];
        if (lane < 32) v2 += Sr[sp * SS + lane + 128];
    }
    int bh = r / NQ, n = r - bh * NQ;
    int b  = bh >> 2, h = bh & 3;
    const float eps = 1e-12f;
    float tp  = temp[h];
    float iqn = tp / fmaxf(sqrtf(nbuf[b * 1280 + h * 160 + n]), eps);       // uniform
    float ik0 = 1.f / fmaxf(sqrtf(nbuf[b * 1280 + 640 + h * 160 + lane]), eps);
    float ik1 = 1.f / fmaxf(sqrtf(nbuf[b * 1280 + 640 + h * 160 + lane + 64]), eps);
    float ik2 = (lane < 32) ? 1.f / fmaxf(sqrtf(nbuf[b * 1280 + 640 + h * 160 + lane + 128]), eps) : 1.f;
    v0 *= iqn * ik0;
    v1 *= iqn * ik1;
    v2 = (lane < 32) ? v2 * iqn * ik2 : -1e30f;
    float mx = fmaxf(fmaxf(v0, v1), v2);
#pragma unroll
    for (int off = 32; off > 0; off >>= 1) mx = fmaxf(mx, __shfl_xor(mx, off));
    float e0 = expf(v0 - mx), e1 = expf(v1 - mx);
    float e2 = (lane < 32) ? expf(v2 - mx) : 0.f;
    float sm = e0 + e1 + e2;
#pragma unroll
    for (int off = 32; off > 0; off >>= 1) sm += __shfl_xor(sm, off);
    float inv = 1.f / sm;
    float* Pb = PT + (size_t)bh * NQ * NQ + n;
    Pb[(size_t)lane * NQ]        = e0 * inv;
    Pb[(size_t)(lane + 64) * NQ] = e1 * inv;
    if (lane < 32) Pb[(size_t)(lane + 128) * NQ] = e2 * inv;
}

// ---------------- Kernel 5: O = P V ----------------------------------------------
__global__ __launch_bounds__(256) void k_pv(const float* __restrict__ Bq,
                                            const float* __restrict__ PT,
                                            float* __restrict__ O) {
    int gblk    = blockIdx.x;                 // 0..1023
    int logical = (gblk & 7) * 128 + (gblk >> 3);
    int nq   = logical & 7;
    int dt   = (logical >> 3) & 7;
    int bh   = logical >> 6;
    int b    = bh >> 2, h = bh & 3;
    int d    = dt * 512 + threadIdx.x * 2;
    int n0   = nq * 20;
    const float* Vb  = Bq + ((size_t)(b * C3 + 128 + h * CPH) * TT) * HW;
    const float* PTb = PT + (size_t)bh * NQ * NQ;
    float* Ob = O + ((size_t)(b * DIM + h * CPH) * TT) * HW;
    float2 acc[20];
#pragma unroll
    for (int j = 0; j < 20; ++j) acc[j] = make_float2(0.f, 0.f);
    for (int m = 0; m < NQ; ++m) {
        float2 vv = *(const float2*)(Vb + (size_t)m * HW + d);
        const float* pr = PTb + m * NQ + n0;      // uniform -> s_load
#pragma unroll
        for (int j = 0; j < 20; ++j) {
            acc[j].x += pr[j] * vv.x;
            acc[j].y += pr[j] * vv.y;
        }
    }
#pragma unroll
    for (int j = 0; j < 20; ++j)
        *(float2*)(Ob + (size_t)(n0 + j) * HW + d) = acc[j];
}

extern "C" void kernel_launch(void* const* d_in, const int* in_sizes, int n_in,
                              void* d_out, int out_size, void* d_ws, size_t ws_size,
                              hipStream_t stream) {
    const float* x    = (const float*)d_in[0];
    const float* wqkv = (const float*)d_in[1];
    const float* wdw  = (const float*)d_in[2];
    const float* wt   = (const float*)d_in[3];
    const float* bt   = (const float*)d_in[4];
    const float* temp = (const float*)d_in[5];
    const float* wout = (const float*)d_in[6];
    float* out = (float*)d_out;

    const size_t SA = (size_t)BB * C3 * TT * HW;       // 31,457,280 floats
    const size_t SN = (size_t)BB * 128 * TT;           // 5,120
    const size_t SS = (size_t)16 * NQ * NQ;            // 409,600
    const size_t SO = (size_t)BB * DIM * TT * HW;      // 10,485,760

    float* bufA = (float*)d_ws;          // region0: qkv-proj out; later reused
    float* bufB = bufA + SA;             // conv+temporal out (q|k|v)
    float* nbuf = bufB + SA;             // q/k row sumsq
    float* wT1  = nbuf + SN;             // transposed w_qkv [64][192]
    float* wT2  = wT1 + 64 * C3;         // transposed w_out [64][64]
    // reuse region0 after k_conv_temporal consumed bufA:
    float* Obuf  = bufA;                 // attn output (SO floats)
    float* Spart = bufA + SO;            // partial scores (NSPLIT*SS floats)
    float* PTbf  = Spart + NSPLIT * SS;  // P^T (SS floats)

    if (ws_size < (2 * SA + SN + 64 * C3 + 64 * DIM) * sizeof(float)) return;

    (void)hipMemsetAsync(nbuf, 0, SN * sizeof(float), stream);

    k_transpose<<<dim3(48), dim3(256), 0, stream>>>(wqkv, wT1, C3, DIM);
    k_transpose<<<dim3(16), dim3(256), 0, stream>>>(wout, wT2, DIM, DIM);

    k_proj<16><<<dim3(160, 12), dim3(256), 0, stream>>>(x, wT1, bufA, C3);
    k_conv_temporal<<<dim3(3072), dim3(256), 0, stream>>>(bufA, wdw, wt, bt, bufB, nbuf);
    k_scores<<<dim3(512), dim3(256), 0, stream>>>(bufB, Spart);
    k_softmax<<<dim3(640), dim3(256), 0, stream>>>(Spart, nbuf, temp, PTbf);
    k_pv<<<dim3(1024), dim3(256), 0, stream>>>(bufB, PTbf, Obuf);
    k_proj<8><<<dim3(160, 8), dim3(256), 0, stream>>>(Obuf, wT2, out, DIM);
}